// Round 1
// baseline (2082.849 us; speedup 1.0000x reference)
//
#include <hip/hip_runtime.h>
#include <math.h>

// Reference: S=128 sequential scan; batches (B=256) are independent chains.
// One workgroup per batch element, 256 threads (4 waves), one CU each.
// Thread t has two roles:
//   v-role (v = t):  input loads, candidate blend, new_rs, output store
//   c-role (c = t):  one NAND-summer choice (dot over V=256 for k=0,1)
// Step-invariant data (weight-row norms, sigmoids, summer_vecs column,
// default column) cached in registers per thread at kernel start.
// L2-bound on the summer_weight stream: 256 WG x 128 steps x 512KB = 16.8 GB.

namespace {

constexpr int S_LEN = 128;
constexpr int V_N   = 256;

__device__ __forceinline__ float sigmoidf_(float x) {
    return 1.0f / (1.0f + expf(-x));
}

__global__ void __launch_bounds__(256) scan_kernel(
    const float* __restrict__ av_g,   // [S,B,V]
    const float* __restrict__ xn_g,   // [S,B,V]
    const float* __restrict__ xv_g,   // [S,B,V]
    const float* __restrict__ yn_g,   // [S,B,V]
    const float* __restrict__ yv_g,   // [S,B,V]
    const float* __restrict__ sv_g,   // [32,256] summer_vecs
    const float* __restrict__ sw_g,   // [256,512] summer_weight (C x 2V)
    const float* __restrict__ snw_g,  // [256,2]  summer_nand_weight
    const float* __restrict__ def_g,  // [4,256]  default
    const float* __restrict__ vnw_g,  // [6,3]    var_nand_weight
    float* __restrict__ out)          // [B,S,V]
{
    const int b    = blockIdx.x;
    const int t    = threadIdx.x;
    const int wave = t >> 6;
    const int lane = t & 63;
    constexpr float EPS = 1e-8f;

    __shared__ __align__(16) float rs_lds[V_N];
    __shared__ __align__(16) float val_lds[V_N];
    __shared__ float wsum[4][8];
    __shared__ float gw[32];

    // ---- step-invariant per-thread caches ----
    float sv_reg[32];                       // summer_vecs column v=t
#pragma unroll
    for (int nc = 0; nc < 32; ++nc) sv_reg[nc] = sv_g[nc * V_N + t];
    float d_reg[4];                         // default column v=t
#pragma unroll
    for (int d = 0; d < 4; ++d) d_reg[d] = def_g[d * V_N + t];
    float nwv[18];                          // sigmoid(var_nand_weight)
#pragma unroll
    for (int i = 0; i < 18; ++i) nwv[i] = sigmoidf_(vnw_g[i]);

    const float4* sw4 = reinterpret_cast<const float4*>(sw_g);

    // weight-row norms for c = t (step-invariant); row = 512 floats = 128 float4
    float n0 = 0.f, n1 = 0.f;
#pragma unroll 4
    for (int i = 0; i < 64; ++i) {
        const float4 w0 = sw4[(size_t)t * 128 + i];
        const float4 w1 = sw4[(size_t)t * 128 + 64 + i];
        n0 += w0.x * w0.x + w0.y * w0.y + w0.z * w0.z + w0.w * w0.w;
        n1 += w1.x * w1.x + w1.y * w1.y + w1.z * w1.z + w1.w * w1.w;
    }
    const float invw0 = 1.0f / fmaxf(sqrtf(n0), EPS);
    const float invw1 = 1.0f / fmaxf(sqrtf(n1), EPS);
    const float nws0  = sigmoidf_(snw_g[2 * t]);
    const float nws1  = sigmoidf_(snw_g[2 * t + 1]);

    const float4* rs4  = reinterpret_cast<const float4*>(rs_lds);
    const float4* val4 = reinterpret_cast<const float4*>(val_lds);

    float rs = 1e-6f;   // running_sum element v=t

    for (int s = 0; s < S_LEN; ++s) {
        const size_t base = (size_t)s * (256 * 256) + (size_t)b * 256 + t;
        const float av = av_g[base];
        const float xn = xn_g[base];
        const float xv = xv_g[base];
        const float yn = yn_g[base];
        const float yv = yv_g[base];

        // ---- phase 1: 7 block reductions (3 dots, 3 sq-norms, |rs|^2) ----
        float p0 = av * xn, p1 = av * yn, p2 = xn * yn;
        float p3 = av * av, p4 = xn * xn, p5 = yn * yn, p6 = rs * rs;
#pragma unroll
        for (int off = 32; off >= 1; off >>= 1) {
            p0 += __shfl_xor(p0, off);
            p1 += __shfl_xor(p1, off);
            p2 += __shfl_xor(p2, off);
            p3 += __shfl_xor(p3, off);
            p4 += __shfl_xor(p4, off);
            p5 += __shfl_xor(p5, off);
            p6 += __shfl_xor(p6, off);
        }
        if (lane == 0) {
            wsum[wave][0] = p0; wsum[wave][1] = p1; wsum[wave][2] = p2;
            wsum[wave][3] = p3; wsum[wave][4] = p4; wsum[wave][5] = p5;
            wsum[wave][6] = p6;
        }
        __syncthreads();   // sync1
        float axn = 0, ayn = 0, xny = 0, naa = 0, nxx = 0, nyy = 0, nrs = 0;
#pragma unroll
        for (int w = 0; w < 4; ++w) {
            axn += wsum[w][0]; ayn += wsum[w][1]; xny += wsum[w][2];
            naa += wsum[w][3]; nxx += wsum[w][4]; nyy += wsum[w][5];
            nrs += wsum[w][6];
        }
        const float na = fmaxf(sqrtf(naa), EPS);
        const float nx = fmaxf(sqrtf(nxx), EPS);
        const float ny = fmaxf(sqrtf(nyy), EPS);
        float csarr[3];
        csarr[0] = axn / (na * nx);
        csarr[1] = ayn / (na * ny);
        csarr[2] = xny / (nx * ny);
        const float inv_rs = 1.0f / fmaxf(sqrtf(nrs), EPS);

        // ---- phase 2: FwdNAND var choice + candidate blend ----
        float vc[6];
#pragma unroll
        for (int j = 0; j < 6; ++j) {
            float p = 1.0f;
#pragma unroll
            for (int k = 0; k < 3; ++k) {
                const float a   = nwv[j * 3 + k];
                const float csk = csarr[k];
                p *= a * csk + (1.0f - a) * (1.0f - csk);
            }
            vc[j] = p;
        }
        const float val = vc[0] * xv + vc[1] * yv + vc[2] * d_reg[0]
                        + vc[3] * d_reg[1] + vc[4] * d_reg[2] + vc[5] * d_reg[3];

        rs_lds[t]  = rs;
        val_lds[t] = val;

        float q0 = val * val;
#pragma unroll
        for (int off = 32; off >= 1; off >>= 1) q0 += __shfl_xor(q0, off);
        if (lane == 0) wsum[wave][7] = q0;
        __syncthreads();   // sync2: nval ready; rs_lds/val_lds visible
        const float nval    = wsum[0][7] + wsum[1][7] + wsum[2][7] + wsum[3][7];
        const float inv_val = 1.0f / fmaxf(sqrtf(nval), EPS);

        // ---- phase 3: NAND summer, c = t (512 MACs/thread from L2) ----
        const float4* wrow = sw4 + (size_t)t * 128;
        float dot0 = 0.f, dot1 = 0.f;
#pragma unroll 8
        for (int i = 0; i < 64; ++i) {
            const float4 w0 = wrow[i];
            const float4 w1 = wrow[64 + i];
            const float4 r  = rs4[i];
            const float4 vv = val4[i];
            dot0 += w0.x * r.x  + w0.y * r.y  + w0.z * r.z  + w0.w * r.w;
            dot1 += w1.x * vv.x + w1.y * vv.y + w1.z * vv.z + w1.w * vv.w;
        }
        float c0 = dot0 * inv_rs  * invw0;
        float c1 = dot1 * inv_val * invw1;
        c0 = (c0 > 0.f) ? c0 : 0.01f * c0;   // leaky_relu
        c1 = (c1 > 0.f) ? c1 : 0.01f * c1;
        const float i0 = nws0 * c0 + (1.0f - nws0) * (1.0f - c0);
        const float i1 = nws1 * c1 + (1.0f - nws1) * (1.0f - c1);
        float choice = i0 * i1;
        // sum over redundancy r within aligned groups of 8 lanes
        choice += __shfl_xor(choice, 1);
        choice += __shfl_xor(choice, 2);
        choice += __shfl_xor(choice, 4);
        if ((t & 7) == 0) gw[t >> 3] = choice;
        __syncthreads();   // sync3: gw ready

        // ---- phase 4: new_rs = summer_vecs^T * gw, store output ----
        float nrs_new = 0.f;
#pragma unroll
        for (int nc = 0; nc < 32; ++nc) nrs_new += sv_reg[nc] * gw[nc];
        rs = nrs_new;
        out[((size_t)b * S_LEN + s) * V_N + t] = rs;
        // no extra sync needed: next-step LDS writes are separated from this
        // step's reads by sync1/sync2 of the next iteration (hazard-checked).
    }
}

} // namespace

extern "C" void kernel_launch(void* const* d_in, const int* in_sizes, int n_in,
                              void* d_out, int out_size, void* d_ws, size_t ws_size,
                              hipStream_t stream) {
    (void)in_sizes; (void)n_in; (void)d_ws; (void)ws_size; (void)out_size;
    const float* av  = (const float*)d_in[0];
    const float* xn  = (const float*)d_in[1];
    const float* xv  = (const float*)d_in[2];
    const float* yn  = (const float*)d_in[3];
    const float* yv  = (const float*)d_in[4];
    const float* sv  = (const float*)d_in[5];
    const float* sw  = (const float*)d_in[6];
    const float* snw = (const float*)d_in[7];
    const float* def = (const float*)d_in[8];
    const float* vnw = (const float*)d_in[9];
    scan_kernel<<<dim3(256), dim3(256), 0, stream>>>(
        av, xn, xv, yn, yv, sv, sw, snw, def, vnw, (float*)d_out);
}

// Round 2
// 2058.437 us; speedup vs baseline: 1.0119x; 1.0119x over previous
//
#include <hip/hip_runtime.h>
#include <hip/hip_fp16.h>
#include <math.h>

// Round 2: weights live in REGISTERS as fp16 (converted once), eliminating the
// per-step 512KB/CU L2 weight stream that made round 1 latency-bound
// (VALUBusy 14.7%, occupancy 12%). 512-thread blocks (8 waves/CU), one per
// batch element. Thread t: c = t&255 (choice row), h = t>>8 (row half).
// Each thread holds 256 f16 weights = 128 VGPRs; rs/val stay fp32 in LDS
// (broadcast reads: wave-uniform address). Norms use the fp16-rounded weights
// so cosines are exact for the perturbed vectors (~1e-3 extra output error).

namespace {

constexpr int S_LEN = 128;
constexpr int V_N   = 256;

__device__ __forceinline__ float sigmoidf_(float x) {
    return 1.0f / (1.0f + expf(-x));
}

__global__ void __launch_bounds__(512) scan_kernel(
    const float* __restrict__ av_g,   // [S,B,V]
    const float* __restrict__ xn_g,
    const float* __restrict__ xv_g,
    const float* __restrict__ yn_g,
    const float* __restrict__ yv_g,
    const float* __restrict__ sv_g,   // [32,256]
    const float* __restrict__ sw_g,   // [256,512]
    const float* __restrict__ snw_g,  // [256,2]
    const float* __restrict__ def_g,  // [4,256]
    const float* __restrict__ vnw_g,  // [6,3]
    float* __restrict__ out)          // [B,S,V]
{
    const int b    = blockIdx.x;
    const int t    = threadIdx.x;
    const int wave = t >> 6;
    const int lane = t & 63;
    const int c    = t & 255;   // choice row
    const int h    = t >> 8;    // row half (uniform per wave)
    constexpr float EPS = 1e-8f;

    __shared__ __align__(16) float rs_lds[V_N];
    __shared__ __align__(16) float val_lds[V_N];
    __shared__ float partials[2][256][2];
    __shared__ float wsum[4][8];
    __shared__ float gw[32];
    __shared__ float sv_lds[32][V_N];
    __shared__ float nwv_lds[18];

    // ---- one-time setup ----
    for (int i = t; i < 32 * V_N; i += 512) sv_lds[i >> 8][i & 255] = sv_g[i];
    if (t < 18) nwv_lds[t] = sigmoidf_(vnw_g[t]);

    // weights: thread (c,h) holds elements [h*128, h*128+128) of k=0 and k=1
    const float4* sw4 = reinterpret_cast<const float4*>(sw_g);
    const float4* p0  = sw4 + (size_t)c * 128 + h * 32;       // k=0 half
    const float4* p1  = p0 + 64;                              // k=1 half
    __half2 w0[64];
    __half2 w1[64];
    float n0 = 0.f, n1 = 0.f;
#pragma unroll
    for (int i = 0; i < 32; ++i) {
        const float4 a  = p0[i];
        const float4 bb = p1[i];
        const __half2 ha0 = __floats2half2_rn(a.x, a.y);
        const __half2 ha1 = __floats2half2_rn(a.z, a.w);
        const __half2 hb0 = __floats2half2_rn(bb.x, bb.y);
        const __half2 hb1 = __floats2half2_rn(bb.z, bb.w);
        w0[2 * i] = ha0; w0[2 * i + 1] = ha1;
        w1[2 * i] = hb0; w1[2 * i + 1] = hb1;
        float2 f;
        f = __half22float2(ha0); n0 += f.x * f.x + f.y * f.y;
        f = __half22float2(ha1); n0 += f.x * f.x + f.y * f.y;
        f = __half22float2(hb0); n1 += f.x * f.x + f.y * f.y;
        f = __half22float2(hb1); n1 += f.x * f.x + f.y * f.y;
    }
    partials[h][c][0] = n0;
    partials[h][c][1] = n1;
    __syncthreads();

    float invw0 = 0.f, invw1 = 0.f, nws0 = 0.f, nws1 = 0.f;
    float d_reg[4] = {0.f, 0.f, 0.f, 0.f};
    if (t < 256) {
        invw0 = 1.0f / fmaxf(sqrtf(partials[0][t][0] + partials[1][t][0]), EPS);
        invw1 = 1.0f / fmaxf(sqrtf(partials[0][t][1] + partials[1][t][1]), EPS);
        nws0  = sigmoidf_(snw_g[2 * t]);
        nws1  = sigmoidf_(snw_g[2 * t + 1]);
#pragma unroll
        for (int d = 0; d < 4; ++d) d_reg[d] = def_g[d * V_N + t];
    }

    const float4* rs4 = reinterpret_cast<const float4*>(rs_lds  + (h << 7));
    const float4* v4  = reinterpret_cast<const float4*>(val_lds + (h << 7));

    float rs = 1e-6f;
    // preload step-0 inputs (v-role threads only)
    float av = 0.f, xn = 0.f, xv = 0.f, yn = 0.f, yv = 0.f;
    if (t < 256) {
        const size_t base0 = (size_t)b * 256 + t;
        av = av_g[base0]; xn = xn_g[base0]; xv = xv_g[base0];
        yn = yn_g[base0]; yv = yv_g[base0];
    }

    for (int s = 0; s < S_LEN; ++s) {
        float inv_rs = 0.f, inv_val = 0.f;
        // ---- phase 1: 7 block reductions over V (t<256) ----
        if (t < 256) {
            float q0 = av * xn, q1 = av * yn, q2 = xn * yn;
            float q3 = av * av, q4 = xn * xn, q5 = yn * yn, q6 = rs * rs;
#pragma unroll
            for (int off = 32; off >= 1; off >>= 1) {
                q0 += __shfl_xor(q0, off);
                q1 += __shfl_xor(q1, off);
                q2 += __shfl_xor(q2, off);
                q3 += __shfl_xor(q3, off);
                q4 += __shfl_xor(q4, off);
                q5 += __shfl_xor(q5, off);
                q6 += __shfl_xor(q6, off);
            }
            if (lane == 0) {
                wsum[wave][0] = q0; wsum[wave][1] = q1; wsum[wave][2] = q2;
                wsum[wave][3] = q3; wsum[wave][4] = q4; wsum[wave][5] = q5;
                wsum[wave][6] = q6;
            }
        }
        __syncthreads();   // sync1

        // ---- phase 2: cs, var-choice blend, stage rs/val (t<256) ----
        if (t < 256) {
            float axn = 0, ayn = 0, xny = 0, naa = 0, nxx = 0, nyy = 0, nrs = 0;
#pragma unroll
            for (int w = 0; w < 4; ++w) {
                axn += wsum[w][0]; ayn += wsum[w][1]; xny += wsum[w][2];
                naa += wsum[w][3]; nxx += wsum[w][4]; nyy += wsum[w][5];
                nrs += wsum[w][6];
            }
            const float na = fmaxf(sqrtf(naa), EPS);
            const float nx = fmaxf(sqrtf(nxx), EPS);
            const float ny = fmaxf(sqrtf(nyy), EPS);
            float csarr[3];
            csarr[0] = axn / (na * nx);
            csarr[1] = ayn / (na * ny);
            csarr[2] = xny / (nx * ny);
            inv_rs = 1.0f / fmaxf(sqrtf(nrs), EPS);

            float vc[6];
#pragma unroll
            for (int j = 0; j < 6; ++j) {
                float p = 1.0f;
#pragma unroll
                for (int k = 0; k < 3; ++k) {
                    const float a   = nwv_lds[j * 3 + k];
                    const float csk = csarr[k];
                    p = p * (a * csk + (1.0f - a) * (1.0f - csk));
                }
                vc[j] = p;
            }
            const float val = vc[0] * xv + vc[1] * yv + vc[2] * d_reg[0]
                            + vc[3] * d_reg[1] + vc[4] * d_reg[2] + vc[5] * d_reg[3];
            rs_lds[t]  = rs;
            val_lds[t] = val;
            float qv = val * val;
#pragma unroll
            for (int off = 32; off >= 1; off >>= 1) qv += __shfl_xor(qv, off);
            if (lane == 0) wsum[wave][7] = qv;
        }
        __syncthreads();   // sync2

        // ---- phase 3: NAND-summer dots, all 512 threads ----
        // prefetch next step's inputs under the dot compute
        float avn = av, xnn = xn, xvn = xv, ynn = yn, yvn = yv;
        if (t < 256) {
            const int sn = (s + 1 < S_LEN) ? s + 1 : s;   // benign reload at tail
            const size_t basen = (size_t)sn * (256 * 256) + (size_t)b * 256 + t;
            avn = av_g[basen]; xnn = xn_g[basen]; xvn = xv_g[basen];
            ynn = yn_g[basen]; yvn = yv_g[basen];
        }
        float dot0 = 0.f, dot1 = 0.f;
#pragma unroll
        for (int i = 0; i < 32; ++i) {
            const float4 r = rs4[i];
            const float4 v = v4[i];
            const float2 a0 = __half22float2(w0[2 * i]);
            const float2 a1 = __half22float2(w0[2 * i + 1]);
            const float2 b0 = __half22float2(w1[2 * i]);
            const float2 b1 = __half22float2(w1[2 * i + 1]);
            dot0 += a0.x * r.x + a0.y * r.y + a1.x * r.z + a1.y * r.w;
            dot1 += b0.x * v.x + b0.y * v.y + b1.x * v.z + b1.y * v.w;
        }
        partials[h][c][0] = dot0;
        partials[h][c][1] = dot1;
        __syncthreads();   // sync3

        // ---- phase 3b: combine halves, NAND, redundancy-reduce (t<256) ----
        if (t < 256) {
            inv_val = 1.0f / fmaxf(sqrtf(wsum[0][7] + wsum[1][7] +
                                         wsum[2][7] + wsum[3][7]), EPS);
            const float d0 = partials[0][t][0] + partials[1][t][0];
            const float d1 = partials[0][t][1] + partials[1][t][1];
            float c0 = d0 * inv_rs  * invw0;
            float c1 = d1 * inv_val * invw1;
            c0 = (c0 > 0.f) ? c0 : 0.01f * c0;
            c1 = (c1 > 0.f) ? c1 : 0.01f * c1;
            const float i0 = nws0 * c0 + (1.0f - nws0) * (1.0f - c0);
            const float i1 = nws1 * c1 + (1.0f - nws1) * (1.0f - c1);
            float choice = i0 * i1;
            choice += __shfl_xor(choice, 1);
            choice += __shfl_xor(choice, 2);
            choice += __shfl_xor(choice, 4);
            if ((t & 7) == 0) gw[t >> 3] = choice;
        }
        __syncthreads();   // sync4

        // ---- phase 4: new_rs, store, rotate prefetched inputs (t<256) ----
        if (t < 256) {
            float nrs_new = 0.f;
#pragma unroll
            for (int nc = 0; nc < 32; ++nc) nrs_new += sv_lds[nc][t] * gw[nc];
            rs = nrs_new;
            out[((size_t)b * S_LEN + s) * V_N + t] = rs;
            av = avn; xn = xnn; xv = xvn; yn = ynn; yv = yvn;
        }
        // LDS hazards separated by >=2 syncs in all cases (checked).
    }
}

} // namespace

extern "C" void kernel_launch(void* const* d_in, const int* in_sizes, int n_in,
                              void* d_out, int out_size, void* d_ws, size_t ws_size,
                              hipStream_t stream) {
    (void)in_sizes; (void)n_in; (void)d_ws; (void)ws_size; (void)out_size;
    const float* av  = (const float*)d_in[0];
    const float* xn  = (const float*)d_in[1];
    const float* xv  = (const float*)d_in[2];
    const float* yn  = (const float*)d_in[3];
    const float* yv  = (const float*)d_in[4];
    const float* sv  = (const float*)d_in[5];
    const float* sw  = (const float*)d_in[6];
    const float* snw = (const float*)d_in[7];
    const float* def = (const float*)d_in[8];
    const float* vnw = (const float*)d_in[9];
    scan_kernel<<<dim3(256), dim3(512), 0, stream>>>(
        av, xn, xv, yn, yv, sv, sw, snw, def, vnw, (float*)d_out);
}